// Round 9
// baseline (256.532 us; speedup 1.0000x reference)
//
#include <hip/hip_runtime.h>
#include <hip/hip_bf16.h>
#include <stdint.h>

// ---------------------------------------------------------------------------
// pcnn round 9: hidden state lives in REGISTERS across all 8 layers.
// Trick: MFMA C-layout (row = 4*quad+reg) vs B-layout (k = 8*quad+j) are both
// lane-column-local permutations, so storing weight OUT-rows pre-permuted by
// pi(m) (pi = 8*(m>>2)+(m&3) | m<16 ; 8*((m-16)>>2)+4+(m&3) | m>=16) makes
// relu(acc) -> v_cvt_pk_bf16 directly produce the next layer's B-fragment
// with channels at natural k-slots. A-fragments keep natural k-order.
// => ZERO LDS traffic in the conv chain; X/Y bf16x8[25] register ping-pong.
// LDS only: input staging (union w/ softmax buf) + in3 + colors = 15.5 KB.
// 1 wave/block, 2048 blocks = 8 waves/CU (VGPR-capped), no barriers.
// ---------------------------------------------------------------------------

typedef short bf16x8 __attribute__((ext_vector_type(8)));
typedef float f32x4  __attribute__((ext_vector_type(4)));

// d_ws: WALL bf16 [8 layers][9 taps][32 o(permuted rows)][32 c] @0 (73728 u16)
//   l=0: conv0 (c<8), l=1..6: mid, l=7: logits (natural rows, o<6)
// f32 @ byte 147456: BALL[8][32](permuted) @0, WPOST[18][3][25] @256, BPOST[18] @1606
#define WSB_N     73728
#define WSF_BYTE  147456
#define WSF_BALL  0
#define WSF_WPOST 256
#define WSF_BPOST 1606
#define WSF_N     1624

__device__ __forceinline__ float b2f(unsigned short u) {
  union { unsigned int u; float f; } v; v.u = ((unsigned int)u) << 16; return v.f;
}
__device__ __forceinline__ unsigned short f2b(float f) {
  union { float f; unsigned int u; } v; v.f = f;
  unsigned int r = v.u + 0x7fffu + ((v.u >> 16) & 1u);  // RNE
  return (unsigned short)(r >> 16);
}
__device__ __forceinline__ unsigned int pk2(float lo, float hi) {
  __hip_bfloat162 h = __float22bfloat162_rn(make_float2(lo, hi));
  union { __hip_bfloat162 h; unsigned int u; } v; v.h = h; return v.u;
}
__device__ __forceinline__ bool sniff_is_f32(const void* w0raw) {
  const unsigned short* q = (const unsigned short*)w0raw;
  int hits = 0;
  #pragma unroll
  for (int i = 0; i < 64; ++i) {
    unsigned int e = (q[i] >> 7) & 0xFFu;
    if (e >= 130u) ++hits;
  }
  return hits > 0;
}
__device__ __forceinline__ float ldw(const void* p, long idx, bool f32) {
  return f32 ? ((const float*)p)[idx] : b2f(((const unsigned short*)p)[idx]);
}
// C-row m -> B-k-slot permutation (see header comment)
__device__ __forceinline__ int kperm(int m) {
  return (m < 16) ? ((m >> 2) * 8 + (m & 3))
                  : (((m - 16) >> 2) * 8 + 4 + (m & 3));
}

// ---------------- weight pre-pack ------------------------------------------
__global__ void prep_weights(const void* __restrict__ w0,
                             const void* __restrict__ b0,
                             const void* __restrict__ wm,
                             const void* __restrict__ bm,
                             const void* __restrict__ wl,
                             const void* __restrict__ bl,
                             const void* __restrict__ wp,
                             const void* __restrict__ bp,
                             unsigned short* __restrict__ wsb,
                             float* __restrict__ wsf) {
  const bool f32 = sniff_is_f32(w0);
  int e = blockIdx.x * blockDim.x + threadIdx.x;
  if (e < WSB_N) {                        // WALL[l][t][o32][c32]
    int l = e / 9216, r = e % 9216, t = r / 1024, r2 = r % 1024;
    int o = r2 >> 5, c = r2 & 31;
    float v = 0.f;
    if (l < 7) {
      int co = kperm(o);                  // original out-channel at row o
      if (co < 25) {
        if (l == 0) { if (c < 8)  v = ldw(w0, (co * 8 + c) * 9 + t, f32); }
        else        { if (c < 25) v = ldw(wm, (((l - 1) * 25 + co) * 25 + c) * 9 + t, f32); }
      }
    } else {
      if (o < 6 && c < 25) v = ldw(wl, (o * 25 + c) * 9 + t, f32);
    }
    wsb[e] = f2b(v);
  } else {
    int q = e - WSB_N;
    if (q < 256) {                        // BALL[l][32] (rows permuted, l<7)
      int l = q >> 5, m = q & 31;
      float v = 0.f;
      if (l < 7) {
        int co = kperm(m);
        if (co < 25) v = (l == 0) ? ldw(b0, co, f32) : ldw(bm, (l - 1) * 25 + co, f32);
      } else {
        if (m < 6) v = ldw(bl, m, f32);
      }
      wsf[WSF_BALL + q] = v;
    } else if (q < 256 + 1350) {
      wsf[WSF_WPOST + (q - 256)] = ldw(wp, q - 256, f32);
    } else if (q < WSF_N) {
      wsf[WSF_BPOST + (q - 1606)] = ldw(bp, q - 1606, f32);
    }
  }
}

// ---------------- main kernel: one wave per 16 patches ---------------------
__global__ __launch_bounds__(64, 2) void pcnn_mfma(
    const void* __restrict__ inp,
    const void* __restrict__ w0raw,
    const unsigned short* __restrict__ wsb,
    const float* __restrict__ wsf,
    void* __restrict__ out) {
  __shared__ __align__(16) unsigned char u9600[9600];  // stage(6400B) then smb(9600B)
  __shared__ float in3[1200];                          // [b16][3c][25px] f32
  __shared__ float colb[288];                          // [b16][18oc]
  short* stage = (short*)u9600;                        // [25px][16b][8c]
  float* smb   = (float*)u9600;                        // [25px][16b][6]

  const bool f32m = sniff_is_f32(w0raw);
  const int lane = threadIdx.x;         // 0..63
  const int col  = lane & 15;           // MFMA n (patch) / m-row group
  const int quad = lane >> 4;
  const long g   = blockIdx.x;          // group of 16 patches

  // ---- stage input [b][8c][25px] -> stage[px][b][c8] + in3 (f32) ----
  for (int e = lane; e < 3200; e += 64) {
    int b = e / 200, r = e % 200, c = r / 25, px = r % 25;
    float v = ldw(inp, g * 3200 + e, f32m);
    stage[px * 128 + b * 8 + c] = f2b(v);
    if (c < 3) in3[b * 75 + c * 25 + px] = v;
  }
  __asm__ volatile("s_waitcnt lgkmcnt(0)" ::: "memory");

  // ---- layer-0 B-frags: quad0 holds ch0..7, other quads zero ----
  bf16x8 X[25], Y[25];
  #pragma unroll
  for (int p = 0; p < 25; ++p) {
    union { bf16x8 v; uint4 q4; } t;
    t.q4 = make_uint4(0u, 0u, 0u, 0u);
    if (quad == 0) t.q4 = *(const uint4*)(stage + p * 128 + col * 8);
    X[p] = t.v;
  }

  // ---- 7 relu conv layers, all in registers ----
  auto conv = [&](const bf16x8 (&in)[25], bf16x8 (&outp)[25], int l) {
    const unsigned short* WA = wsb + l * 9216;
    const f32x4 bias0 = *(const f32x4*)(wsf + WSF_BALL + l * 32 + quad * 4);
    const f32x4 bias1 = *(const f32x4*)(wsf + WSF_BALL + l * 32 + 16 + quad * 4);
    #pragma unroll
    for (int p = 0; p < 25; ++p) {
      const int py = p / 5, pxx = p % 5;
      f32x4 a0 = bias0, a1 = bias1;
      #pragma unroll
      for (int dy = -1; dy <= 1; ++dy)
        #pragma unroll
        for (int dx = -1; dx <= 1; ++dx)
          if ((unsigned)(py + dy) < 5u && (unsigned)(pxx + dx) < 5u) {
            const int t = (dy + 1) * 3 + (dx + 1);
            const int q = p + dy * 5 + dx;
            bf16x8 A0t = *(const bf16x8*)(WA + t * 1024 + col * 32 + quad * 8);
            bf16x8 A1t = *(const bf16x8*)(WA + t * 1024 + (16 + col) * 32 + quad * 8);
            a0 = __builtin_amdgcn_mfma_f32_16x16x32_bf16(A0t, in[q], a0, 0, 0, 0);
            a1 = __builtin_amdgcn_mfma_f32_16x16x32_bf16(A1t, in[q], a1, 0, 0, 0);
          }
      // relu + pack: with permuted weight rows this IS the next B-frag
      union { bf16x8 v; unsigned int uu[4]; } nb;
      nb.uu[0] = pk2(fmaxf(a0[0], 0.f), fmaxf(a0[1], 0.f));
      nb.uu[1] = pk2(fmaxf(a0[2], 0.f), fmaxf(a0[3], 0.f));
      nb.uu[2] = pk2(fmaxf(a1[0], 0.f), fmaxf(a1[1], 0.f));
      nb.uu[3] = pk2(fmaxf(a1[2], 0.f), fmaxf(a1[3], 0.f));
      outp[p] = nb.v;
    }
  };

  #pragma unroll 1
  for (int l = 0; l < 7; ++l) {
    if (l & 1) conv(Y, X, l);
    else       conv(X, Y, l);
  }
  // final hidden in Y (l=6 even: X->Y)

  // ---- logits (natural rows, o<6) + in-register softmax -> smb ----
  {
    const unsigned short* WA = wsb + 7 * 9216;
    const f32x4 biasl = *(const f32x4*)(wsf + WSF_BALL + 7 * 32 + quad * 4);
    #pragma unroll
    for (int p = 0; p < 25; ++p) {
      const int py = p / 5, pxx = p % 5;
      f32x4 a = biasl;
      #pragma unroll
      for (int dy = -1; dy <= 1; ++dy)
        #pragma unroll
        for (int dx = -1; dx <= 1; ++dx)
          if ((unsigned)(py + dy) < 5u && (unsigned)(pxx + dx) < 5u) {
            const int t = (dy + 1) * 3 + (dx + 1);
            const int q = p + dy * 5 + dx;
            bf16x8 At = *(const bf16x8*)(WA + t * 1024 + col * 32 + quad * 8);
            a = __builtin_amdgcn_mfma_f32_16x16x32_bf16(At, Y[q], a, 0, 0, 0);
          }
      // quad0: rows0-3 = ch0-3; quad1 regs0,1 = ch4,5 (pull via xor 16)
      float l4 = __shfl_xor(a[0], 16);
      float l5 = __shfl_xor(a[1], 16);
      if (quad == 0) {
        float m = fmaxf(fmaxf(fmaxf(a[0], a[1]), fmaxf(a[2], a[3])), fmaxf(l4, l5));
        float e0 = __expf(a[0] - m), e1 = __expf(a[1] - m), e2 = __expf(a[2] - m);
        float e3 = __expf(a[3] - m), e4 = __expf(l4 - m), e5 = __expf(l5 - m);
        float inv = 1.f / (e0 + e1 + e2 + e3 + e4 + e5);
        float* sp = smb + p * 96 + col * 6;
        sp[0] = e0 * inv; sp[1] = e1 * inv; sp[2] = e2 * inv;
        sp[3] = e3 * inv; sp[4] = e4 * inv; sp[5] = e5 * inv;
      }
    }
  }
  __asm__ volatile("s_waitcnt lgkmcnt(0)" ::: "memory");

  // ---- colors: 5x5 VALID conv on first 3 input channels (from in3) ----
  for (int j = lane; j < 288; j += 64) {
    int b = j / 18, oc = j % 18;
    float s = wsf[WSF_BPOST + oc];
    #pragma unroll
    for (int ic = 0; ic < 3; ++ic)
      #pragma unroll
      for (int px = 0; px < 25; ++px)
        s = fmaf(wsf[WSF_WPOST + (oc * 3 + ic) * 25 + px], in3[b * 75 + ic * 25 + px], s);
    colb[b * 18 + oc] = s;
  }
  __asm__ volatile("s_waitcnt lgkmcnt(0)" ::: "memory");

  // ---- mix + store: out[b][c][p] = sum_w colors[b][c*6+w] * sm[p][b][w] ----
  for (int e = lane; e < 1200; e += 64) {
    int b = e / 75, r = e % 75, c = r / 25, p = r % 25;
    float v = 0.f;
    #pragma unroll
    for (int w = 0; w < 6; ++w)
      v = fmaf(colb[b * 18 + c * 6 + w], smb[p * 96 + b * 6 + w], v);
    const long oidx = g * 1200 + e;
    if (f32m) ((float*)out)[oidx] = v;
    else      ((unsigned short*)out)[oidx] = f2b(v);
  }
}

extern "C" void kernel_launch(void* const* d_in, const int* in_sizes, int n_in,
                              void* d_out, int out_size, void* d_ws, size_t ws_size,
                              hipStream_t stream) {
  unsigned short* wsb = (unsigned short*)d_ws;
  float* wsf = (float*)((char*)d_ws + WSF_BYTE);
  const int B = in_sizes[0] / 200;  // 32768

  const int prep_n = WSB_N + WSF_N;  // 75352
  prep_weights<<<(prep_n + 255) / 256, 256, 0, stream>>>(
      d_in[1], d_in[2], d_in[3], d_in[4], d_in[5], d_in[6], d_in[7], d_in[8],
      wsb, wsf);
  pcnn_mfma<<<B / 16, 64, 0, stream>>>(d_in[0], d_in[1], wsb, wsf, d_out);
}

// Round 10
// 176.993 us; speedup vs baseline: 1.4494x; 1.4494x over previous
//
#include <hip/hip_runtime.h>
#include <hip/hip_bf16.h>
#include <stdint.h>

// ---------------------------------------------------------------------------
// pcnn round 10: register-resident hidden state, fixed liveness (R9 redo).
//  - Layer-pair loop: conv(X->Y,0); 3x { conv(Y->X), conv(X->Y) } -> only ONE
//    100-VGPR array live across the back edge; X dies as Y fills inside.
//  - 18 A-frags hoisted per layer (was per-pixel-per-tap in R9 -> 450 loads).
//  - amdgpu_waves_per_eu(2,2): pin allocator to 256-VGPR budget, 2 waves/EU.
//  - Permuted weight rows (kperm) make relu(acc)+cvt_pk the next B-frag
//    (verified R9: absmax 0.0156). Zero LDS in the conv chain; no barriers.
// ---------------------------------------------------------------------------

typedef short bf16x8 __attribute__((ext_vector_type(8)));
typedef float f32x4  __attribute__((ext_vector_type(4)));

// d_ws: WALL bf16 [8 layers][9 taps][32 o(permuted rows)][32 c] @0 (73728 u16)
//   l=0: conv0 (c<8), l=1..6: mid, l=7: logits (natural rows, o<6)
// f32 @ byte 147456: BALL[8][32](permuted) @0, WPOST[18][3][25] @256, BPOST[18] @1606
#define WSB_N     73728
#define WSF_BYTE  147456
#define WSF_BALL  0
#define WSF_WPOST 256
#define WSF_BPOST 1606
#define WSF_N     1624

__device__ __forceinline__ float b2f(unsigned short u) {
  union { unsigned int u; float f; } v; v.u = ((unsigned int)u) << 16; return v.f;
}
__device__ __forceinline__ unsigned short f2b(float f) {
  union { float f; unsigned int u; } v; v.f = f;
  unsigned int r = v.u + 0x7fffu + ((v.u >> 16) & 1u);  // RNE
  return (unsigned short)(r >> 16);
}
__device__ __forceinline__ unsigned int pk2(float lo, float hi) {
  __hip_bfloat162 h = __float22bfloat162_rn(make_float2(lo, hi));
  union { __hip_bfloat162 h; unsigned int u; } v; v.h = h; return v.u;
}
__device__ __forceinline__ bool sniff_is_f32(const void* w0raw) {
  const unsigned short* q = (const unsigned short*)w0raw;
  int hits = 0;
  #pragma unroll
  for (int i = 0; i < 64; ++i) {
    unsigned int e = (q[i] >> 7) & 0xFFu;
    if (e >= 130u) ++hits;
  }
  return hits > 0;
}
__device__ __forceinline__ float ldw(const void* p, long idx, bool f32) {
  return f32 ? ((const float*)p)[idx] : b2f(((const unsigned short*)p)[idx]);
}
// C-row m -> B-k-slot permutation
__device__ __forceinline__ int kperm(int m) {
  return (m < 16) ? ((m >> 2) * 8 + (m & 3))
                  : (((m - 16) >> 2) * 8 + 4 + (m & 3));
}

// ---------------- weight pre-pack (identical to R9, verified) --------------
__global__ void prep_weights(const void* __restrict__ w0,
                             const void* __restrict__ b0,
                             const void* __restrict__ wm,
                             const void* __restrict__ bm,
                             const void* __restrict__ wl,
                             const void* __restrict__ bl,
                             const void* __restrict__ wp,
                             const void* __restrict__ bp,
                             unsigned short* __restrict__ wsb,
                             float* __restrict__ wsf) {
  const bool f32 = sniff_is_f32(w0);
  int e = blockIdx.x * blockDim.x + threadIdx.x;
  if (e < WSB_N) {                        // WALL[l][t][o32][c32]
    int l = e / 9216, r = e % 9216, t = r / 1024, r2 = r % 1024;
    int o = r2 >> 5, c = r2 & 31;
    float v = 0.f;
    if (l < 7) {
      int co = kperm(o);                  // original out-channel at row o
      if (co < 25) {
        if (l == 0) { if (c < 8)  v = ldw(w0, (co * 8 + c) * 9 + t, f32); }
        else        { if (c < 25) v = ldw(wm, (((l - 1) * 25 + co) * 25 + c) * 9 + t, f32); }
      }
    } else {
      if (o < 6 && c < 25) v = ldw(wl, (o * 25 + c) * 9 + t, f32);
    }
    wsb[e] = f2b(v);
  } else {
    int q = e - WSB_N;
    if (q < 256) {                        // BALL[l][32] (rows permuted, l<7)
      int l = q >> 5, m = q & 31;
      float v = 0.f;
      if (l < 7) {
        int co = kperm(m);
        if (co < 25) v = (l == 0) ? ldw(b0, co, f32) : ldw(bm, (l - 1) * 25 + co, f32);
      } else {
        if (m < 6) v = ldw(bl, m, f32);
      }
      wsf[WSF_BALL + q] = v;
    } else if (q < 256 + 1350) {
      wsf[WSF_WPOST + (q - 256)] = ldw(wp, q - 256, f32);
    } else if (q < WSF_N) {
      wsf[WSF_BPOST + (q - 1606)] = ldw(bp, q - 1606, f32);
    }
  }
}

// ---------------- main kernel: one wave per 16 patches ---------------------
__global__ __launch_bounds__(64)
__attribute__((amdgpu_waves_per_eu(2, 2)))
void pcnn_mfma(
    const void* __restrict__ inp,
    const void* __restrict__ w0raw,
    const unsigned short* __restrict__ wsb,
    const float* __restrict__ wsf,
    void* __restrict__ out) {
  __shared__ __align__(16) unsigned char u9600[9600];  // stage(6400B) then smb(9600B)
  __shared__ float in3[1200];                          // [b16][3c][25px] f32
  __shared__ float colb[288];                          // [b16][18oc]
  short* stage = (short*)u9600;                        // [25px][16b][8c]
  float* smb   = (float*)u9600;                        // [25px][16b][6]

  const bool f32m = sniff_is_f32(w0raw);
  const int lane = threadIdx.x;         // 0..63
  const int col  = lane & 15;           // MFMA n (patch) / m-row group
  const int quad = lane >> 4;
  const long g   = blockIdx.x;          // group of 16 patches

  // ---- stage input [b][8c][25px] -> stage[px][b][c8] + in3 (f32) ----
  for (int e = lane; e < 3200; e += 64) {
    int b = e / 200, r = e % 200, c = r / 25, px = r % 25;
    float v = ldw(inp, g * 3200 + e, f32m);
    stage[px * 128 + b * 8 + c] = f2b(v);
    if (c < 3) in3[b * 75 + c * 25 + px] = v;
  }
  __asm__ volatile("s_waitcnt lgkmcnt(0)" ::: "memory");

  // ---- layer-0 B-frags: quad0 holds ch0..7, other quads zero ----
  bf16x8 X[25], Y[25];
  #pragma unroll
  for (int p = 0; p < 25; ++p) {
    union { bf16x8 v; uint4 q4; } t;
    t.q4 = make_uint4(0u, 0u, 0u, 0u);
    if (quad == 0) t.q4 = *(const uint4*)(stage + p * 128 + col * 8);
    X[p] = t.v;
  }

  // ---- conv layer: A-frags hoisted, px loop fully unrolled ----
  auto conv = [&](const bf16x8 (&in)[25], bf16x8 (&outp)[25], int l) {
    const unsigned short* WA = wsb + l * 9216;
    bf16x8 A0[9], A1[9];
    #pragma unroll
    for (int t = 0; t < 9; ++t) {
      A0[t] = *(const bf16x8*)(WA + t * 1024 + col * 32 + quad * 8);
      A1[t] = *(const bf16x8*)(WA + t * 1024 + (16 + col) * 32 + quad * 8);
    }
    const f32x4 bias0 = *(const f32x4*)(wsf + WSF_BALL + l * 32 + quad * 4);
    const f32x4 bias1 = *(const f32x4*)(wsf + WSF_BALL + l * 32 + 16 + quad * 4);
    #pragma unroll
    for (int p = 0; p < 25; ++p) {
      const int py = p / 5, pxx = p % 5;
      f32x4 a0 = bias0, a1 = bias1;
      #pragma unroll
      for (int dy = -1; dy <= 1; ++dy)
        #pragma unroll
        for (int dx = -1; dx <= 1; ++dx)
          if ((unsigned)(py + dy) < 5u && (unsigned)(pxx + dx) < 5u) {
            const int t = (dy + 1) * 3 + (dx + 1);
            const int q = p + dy * 5 + dx;
            a0 = __builtin_amdgcn_mfma_f32_16x16x32_bf16(A0[t], in[q], a0, 0, 0, 0);
            a1 = __builtin_amdgcn_mfma_f32_16x16x32_bf16(A1[t], in[q], a1, 0, 0, 0);
          }
      // relu + pack: with permuted weight rows this IS the next B-frag
      union { bf16x8 v; unsigned int uu[4]; } nb;
      nb.uu[0] = pk2(fmaxf(a0[0], 0.f), fmaxf(a0[1], 0.f));
      nb.uu[1] = pk2(fmaxf(a0[2], 0.f), fmaxf(a0[3], 0.f));
      nb.uu[2] = pk2(fmaxf(a1[0], 0.f), fmaxf(a1[1], 0.f));
      nb.uu[3] = pk2(fmaxf(a1[2], 0.f), fmaxf(a1[3], 0.f));
      outp[p] = nb.v;
    }
  };

  // layers: 0: X->Y; then pairs {Y->X, X->Y} so only ONE array crosses the
  // back edge (100 VGPRs), letting in/out liveness interleave inside.
  conv(X, Y, 0);
  #pragma unroll 1
  for (int i = 0; i < 3; ++i) {
    conv(Y, X, 2 * i + 1);
    conv(X, Y, 2 * i + 2);
  }
  // final hidden in Y

  // ---- logits (natural rows, o<6) + in-register softmax -> smb ----
  {
    const unsigned short* WA = wsb + 7 * 9216;
    bf16x8 A[9];
    #pragma unroll
    for (int t = 0; t < 9; ++t)
      A[t] = *(const bf16x8*)(WA + t * 1024 + col * 32 + quad * 8);
    const f32x4 biasl = *(const f32x4*)(wsf + WSF_BALL + 7 * 32 + quad * 4);
    #pragma unroll
    for (int p = 0; p < 25; ++p) {
      const int py = p / 5, pxx = p % 5;
      f32x4 a = biasl;
      #pragma unroll
      for (int dy = -1; dy <= 1; ++dy)
        #pragma unroll
        for (int dx = -1; dx <= 1; ++dx)
          if ((unsigned)(py + dy) < 5u && (unsigned)(pxx + dx) < 5u) {
            const int t = (dy + 1) * 3 + (dx + 1);
            const int q = p + dy * 5 + dx;
            a = __builtin_amdgcn_mfma_f32_16x16x32_bf16(A[t], Y[q], a, 0, 0, 0);
          }
      // quad0: rows0-3 = ch0-3; quad1 regs0,1 = ch4,5 (pull via xor 16)
      float l4 = __shfl_xor(a[0], 16);
      float l5 = __shfl_xor(a[1], 16);
      if (quad == 0) {
        float m = fmaxf(fmaxf(fmaxf(a[0], a[1]), fmaxf(a[2], a[3])), fmaxf(l4, l5));
        float e0 = __expf(a[0] - m), e1 = __expf(a[1] - m), e2 = __expf(a[2] - m);
        float e3 = __expf(a[3] - m), e4 = __expf(l4 - m), e5 = __expf(l5 - m);
        float inv = 1.f / (e0 + e1 + e2 + e3 + e4 + e5);
        float* sp = smb + p * 96 + col * 6;
        sp[0] = e0 * inv; sp[1] = e1 * inv; sp[2] = e2 * inv;
        sp[3] = e3 * inv; sp[4] = e4 * inv; sp[5] = e5 * inv;
      }
    }
  }
  __asm__ volatile("s_waitcnt lgkmcnt(0)" ::: "memory");

  // ---- colors: 5x5 VALID conv on first 3 input channels (from in3) ----
  for (int j = lane; j < 288; j += 64) {
    int b = j / 18, oc = j % 18;
    float s = wsf[WSF_BPOST + oc];
    #pragma unroll
    for (int ic = 0; ic < 3; ++ic)
      #pragma unroll
      for (int px = 0; px < 25; ++px)
        s = fmaf(wsf[WSF_WPOST + (oc * 3 + ic) * 25 + px], in3[b * 75 + ic * 25 + px], s);
    colb[b * 18 + oc] = s;
  }
  __asm__ volatile("s_waitcnt lgkmcnt(0)" ::: "memory");

  // ---- mix + store: out[b][c][p] = sum_w colors[b][c*6+w] * sm[p][b][w] ----
  for (int e = lane; e < 1200; e += 64) {
    int b = e / 75, r = e % 75, c = r / 25, p = r % 25;
    float v = 0.f;
    #pragma unroll
    for (int w = 0; w < 6; ++w)
      v = fmaf(colb[b * 18 + c * 6 + w], smb[p * 96 + b * 6 + w], v);
    const long oidx = g * 1200 + e;
    if (f32m) ((float*)out)[oidx] = v;
    else      ((unsigned short*)out)[oidx] = f2b(v);
  }
}

extern "C" void kernel_launch(void* const* d_in, const int* in_sizes, int n_in,
                              void* d_out, int out_size, void* d_ws, size_t ws_size,
                              hipStream_t stream) {
  unsigned short* wsb = (unsigned short*)d_ws;
  float* wsf = (float*)((char*)d_ws + WSF_BYTE);
  const int B = in_sizes[0] / 200;  // 32768

  const int prep_n = WSB_N + WSF_N;  // 75352
  prep_weights<<<(prep_n + 255) / 256, 256, 0, stream>>>(
      d_in[1], d_in[2], d_in[3], d_in[4], d_in[5], d_in[6], d_in[7], d_in[8],
      wsb, wsf);
  pcnn_mfma<<<B / 16, 64, 0, stream>>>(d_in[0], d_in[1], wsb, wsf, d_out);
}